// Round 1
// baseline (499.024 us; speedup 1.0000x reference)
//
#include <hip/hip_runtime.h>
#include <hip/hip_bf16.h>

#define B_ 2
#define S_ 512
#define D_ 768
#define NH 12
#define HD 64

// ---------------------------------------------------------------------------
// Kernel 1: fused QKV projection.
// out[m,n] = sum_d hidden[m,d] * W[n,d] + bias[n], written to ws in
// (B, NH, S, HD) layout. q is pre-scaled by 1/sqrt(HD).
// Tiles: BM=64, BN=64, BK=16; 256 threads, 4x4 per thread.
// ---------------------------------------------------------------------------
__global__ __launch_bounds__(256) void qkv_gemm(
    const float* __restrict__ A,
    const float* __restrict__ Wq, const float* __restrict__ Wk, const float* __restrict__ Wv,
    const float* __restrict__ bq, const float* __restrict__ bk, const float* __restrict__ bv,
    float* __restrict__ qws, float* __restrict__ kws, float* __restrict__ vws)
{
    __shared__ float As[16][68];
    __shared__ float Bs[16][68];

    const int m0  = blockIdx.x * 64;
    const int yt  = blockIdx.y;          // 0..35
    const int mat = yt / 12;             // 0=q 1=k 2=v
    const int n0  = (yt % 12) * 64;

    const float* W    = (mat == 0) ? Wq : ((mat == 1) ? Wk : Wv);
    const float* bias = (mat == 0) ? bq : ((mat == 1) ? bk : bv);

    const int tid  = threadIdx.x;
    const int lRow = tid >> 2;           // 0..63
    const int lK   = (tid & 3) * 4;      // 0,4,8,12
    const int tRow = (tid >> 4) * 4;     // 0..60
    const int tCol = (tid & 15) * 4;     // 0..60

    float acc[4][4] = {};

    for (int k0 = 0; k0 < D_; k0 += 16) {
        float4 a4 = *(const float4*)(A + (size_t)(m0 + lRow) * D_ + k0 + lK);
        float4 b4 = *(const float4*)(W + (size_t)(n0 + lRow) * D_ + k0 + lK);
        As[lK + 0][lRow] = a4.x; As[lK + 1][lRow] = a4.y;
        As[lK + 2][lRow] = a4.z; As[lK + 3][lRow] = a4.w;
        Bs[lK + 0][lRow] = b4.x; Bs[lK + 1][lRow] = b4.y;
        Bs[lK + 2][lRow] = b4.z; Bs[lK + 3][lRow] = b4.w;
        __syncthreads();

        #pragma unroll
        for (int kk = 0; kk < 16; ++kk) {
            float4 av = *(const float4*)&As[kk][tRow];
            float4 bv = *(const float4*)&Bs[kk][tCol];
            float ar[4] = {av.x, av.y, av.z, av.w};
            float br[4] = {bv.x, bv.y, bv.z, bv.w};
            #pragma unroll
            for (int i = 0; i < 4; ++i)
                #pragma unroll
                for (int j = 0; j < 4; ++j)
                    acc[i][j] += ar[i] * br[j];
        }
        __syncthreads();
    }

    #pragma unroll
    for (int i = 0; i < 4; ++i) {
        const int m = m0 + tRow + i;
        const int b = m >> 9;            // m / 512
        const int s = m & 511;
        #pragma unroll
        for (int j = 0; j < 4; ++j) {
            const int n    = n0 + tCol + j;
            const int head = n >> 6;
            const int h    = n & 63;
            float v = acc[i][j] + bias[n];
            const size_t dst = (((size_t)(b * NH + head) * S_) + s) * HD + h;
            if (mat == 0)      qws[dst] = v * 0.125f;   // 1/sqrt(64)
            else if (mat == 1) kws[dst] = v;
            else               vws[dst] = v;
        }
    }
}

// ---------------------------------------------------------------------------
// Kernel 2: attention. One block per (b, s) row; all 12 heads in-block so the
// rel tensors are read exactly once. PB-Relax softmax == plain softmax
// (shift invariance), done with standard max subtraction.
// ---------------------------------------------------------------------------
__global__ __launch_bounds__(256) void attn_kernel(
    const float* __restrict__ qws, const float* __restrict__ kws, const float* __restrict__ vws,
    const float* __restrict__ rel1, const float* __restrict__ rel2, const float* __restrict__ rel3,
    const float* __restrict__ mask, float* __restrict__ out)
{
    __shared__ float qs_l[NH][HD];
    __shared__ float sc[NH][S_];

    const int bs  = blockIdx.x;
    const int b   = bs >> 9;
    const int s   = bs & 511;
    const int tid = threadIdx.x;

    // Phase A: stage scaled q for all heads.
    for (int idx = tid; idx < NH * HD; idx += 256) {
        const int n = idx >> 6, h = idx & 63;
        qs_l[n][h] = qws[(((size_t)(b * NH + n) * S_) + s) * HD + h];
    }
    __syncthreads();

    // Phase B: scores. Each thread owns 2 k values.
    for (int rep = 0; rep < 2; ++rep) {
        const int k = rep * 256 + tid;
        const size_t rbase = (((size_t)(b * S_ + s)) * S_ + k) * HD;
        const float4* r1 = (const float4*)(rel1 + rbase);
        const float4* r2 = (const float4*)(rel2 + rbase);
        const float4* r3 = (const float4*)(rel3 + rbase);

        float4 rs[16];
        #pragma unroll
        for (int j = 0; j < 16; ++j) {
            float4 a = r1[j], bb = r2[j], c = r3[j];
            rs[j].x = a.x + bb.x + c.x;
            rs[j].y = a.y + bb.y + c.y;
            rs[j].z = a.z + bb.z + c.z;
            rs[j].w = a.w + bb.w + c.w;
        }
        const float msk = mask[b * S_ + k];

        for (int n = 0; n < NH; ++n) {
            const float4* kp = (const float4*)(kws + (((size_t)(b * NH + n) * S_) + k) * HD);
            const float4* qp = (const float4*)(&qs_l[n][0]);
            float acc = 0.f;
            #pragma unroll
            for (int j = 0; j < 16; ++j) {
                float4 kv = kp[j];
                float4 qv = qp[j];
                acc += qv.x * (kv.x + rs[j].x) + qv.y * (kv.y + rs[j].y)
                     + qv.z * (kv.z + rs[j].z) + qv.w * (kv.w + rs[j].w);
            }
            sc[n][k] = acc + msk;
        }
    }
    __syncthreads();

    // Phase C: softmax per head row, wave-parallel (4 waves x 3 rows each).
    const int wave = tid >> 6, lane = tid & 63;
    for (int n = wave; n < NH; n += 4) {
        float vals[8];
        float m = -1e30f;
        #pragma unroll
        for (int i = 0; i < 8; ++i) { vals[i] = sc[n][lane + 64 * i]; m = fmaxf(m, vals[i]); }
        #pragma unroll
        for (int off = 32; off >= 1; off >>= 1) m = fmaxf(m, __shfl_xor(m, off));
        float sum = 0.f;
        #pragma unroll
        for (int i = 0; i < 8; ++i) { vals[i] = __expf(vals[i] - m); sum += vals[i]; }
        #pragma unroll
        for (int off = 32; off >= 1; off >>= 1) sum += __shfl_xor(sum, off);
        const float inv = 1.0f / sum;
        #pragma unroll
        for (int i = 0; i < 8; ++i) sc[n][lane + 64 * i] = vals[i] * inv;
    }
    __syncthreads();

    // Phase D: ctx = probs @ V. Thread owns 3 (n,h) pairs (tid, tid+256, tid+512).
    {
        const int p0 = tid, p1 = tid + 256, p2 = tid + 512;
        const int n0 = p0 >> 6, n1 = p1 >> 6, n2 = p2 >> 6;
        const int h  = p0 & 63;
        const float* v0 = vws + (((size_t)(b * NH + n0) * S_)) * HD + h;
        const float* v1 = vws + (((size_t)(b * NH + n1) * S_)) * HD + h;
        const float* v2 = vws + (((size_t)(b * NH + n2) * S_)) * HD + h;
        float a0 = 0.f, a1 = 0.f, a2 = 0.f;
        #pragma unroll 4
        for (int k = 0; k < S_; ++k) {
            a0 += sc[n0][k] * v0[(size_t)k * HD];
            a1 += sc[n1][k] * v1[(size_t)k * HD];
            a2 += sc[n2][k] * v2[(size_t)k * HD];
        }
        float* o = out + ((size_t)(b * S_ + s)) * D_;
        o[p0] = a0; o[p1] = a1; o[p2] = a2;
    }
}

extern "C" void kernel_launch(void* const* d_in, const int* in_sizes, int n_in,
                              void* d_out, int out_size, void* d_ws, size_t ws_size,
                              hipStream_t stream) {
    const float* hidden = (const float*)d_in[0];
    const float* mask   = (const float*)d_in[1];
    const float* rel1   = (const float*)d_in[2];
    const float* rel2   = (const float*)d_in[3];
    const float* rel3   = (const float*)d_in[4];
    const float* Wq     = (const float*)d_in[5];
    const float* bq     = (const float*)d_in[6];
    const float* Wk     = (const float*)d_in[7];
    const float* bk     = (const float*)d_in[8];
    const float* Wv     = (const float*)d_in[9];
    const float* bv     = (const float*)d_in[10];
    float* out = (float*)d_out;

    const size_t per = (size_t)B_ * NH * S_ * HD;   // 786432 floats
    float* qws = (float*)d_ws;
    float* kws = qws + per;
    float* vws = kws + per;

    dim3 ggrid(B_ * S_ / 64, 36);
    qkv_gemm<<<ggrid, 256, 0, stream>>>(hidden, Wq, Wk, Wv, bq, bk, bv, qws, kws, vws);

    attn_kernel<<<B_ * S_, 256, 0, stream>>>(qws, kws, vws, rel1, rel2, rel3, mask, out);
}

// Round 2
// 262.462 us; speedup vs baseline: 1.9013x; 1.9013x over previous
//
#include <hip/hip_runtime.h>
#include <hip/hip_bf16.h>

#define B_ 2
#define S_ 512
#define D_ 768
#define NH 12
#define HD 64

// ---------------------------------------------------------------------------
// Kernel 1: fused QKV projection -> ws in (B, NH, S, HD) layout.
// q pre-scaled by 1/sqrt(HD).
// ---------------------------------------------------------------------------
__global__ __launch_bounds__(256) void qkv_gemm(
    const float* __restrict__ A,
    const float* __restrict__ Wq, const float* __restrict__ Wk, const float* __restrict__ Wv,
    const float* __restrict__ bq, const float* __restrict__ bk, const float* __restrict__ bv,
    float* __restrict__ qws, float* __restrict__ kws, float* __restrict__ vws)
{
    __shared__ float As[16][68];
    __shared__ float Bs[16][68];

    const int m0  = blockIdx.x * 64;
    const int yt  = blockIdx.y;          // 0..35
    const int mat = yt / 12;             // 0=q 1=k 2=v
    const int n0  = (yt % 12) * 64;

    const float* W    = (mat == 0) ? Wq : ((mat == 1) ? Wk : Wv);
    const float* bias = (mat == 0) ? bq : ((mat == 1) ? bk : bv);

    const int tid  = threadIdx.x;
    const int lRow = tid >> 2;           // 0..63
    const int lK   = (tid & 3) * 4;      // 0,4,8,12
    const int tRow = (tid >> 4) * 4;     // 0..60
    const int tCol = (tid & 15) * 4;     // 0..60

    float acc[4][4] = {};

    for (int k0 = 0; k0 < D_; k0 += 16) {
        float4 a4 = *(const float4*)(A + (size_t)(m0 + lRow) * D_ + k0 + lK);
        float4 b4 = *(const float4*)(W + (size_t)(n0 + lRow) * D_ + k0 + lK);
        As[lK + 0][lRow] = a4.x; As[lK + 1][lRow] = a4.y;
        As[lK + 2][lRow] = a4.z; As[lK + 3][lRow] = a4.w;
        Bs[lK + 0][lRow] = b4.x; Bs[lK + 1][lRow] = b4.y;
        Bs[lK + 2][lRow] = b4.z; Bs[lK + 3][lRow] = b4.w;
        __syncthreads();

        #pragma unroll
        for (int kk = 0; kk < 16; ++kk) {
            float4 av = *(const float4*)&As[kk][tRow];
            float4 bv4 = *(const float4*)&Bs[kk][tCol];
            float ar[4] = {av.x, av.y, av.z, av.w};
            float br[4] = {bv4.x, bv4.y, bv4.z, bv4.w};
            #pragma unroll
            for (int i = 0; i < 4; ++i)
                #pragma unroll
                for (int j = 0; j < 4; ++j)
                    acc[i][j] += ar[i] * br[j];
        }
        __syncthreads();
    }

    #pragma unroll
    for (int i = 0; i < 4; ++i) {
        const int m = m0 + tRow + i;
        const int b = m >> 9;
        const int s = m & 511;
        #pragma unroll
        for (int j = 0; j < 4; ++j) {
            const int n    = n0 + tCol + j;
            const int head = n >> 6;
            const int h    = n & 63;
            float v = acc[i][j] + bias[n];
            const size_t dst = (((size_t)(b * NH + head) * S_) + s) * HD + h;
            if (mat == 0)      qws[dst] = v * 0.125f;   // 1/sqrt(64)
            else if (mat == 1) kws[dst] = v;
            else               vws[dst] = v;
        }
    }
}

// ---------------------------------------------------------------------------
// Kernel 2: scores[b][n][s][k] = qs . (K + r1 + r2 + r3) + mask.
// Grid: (kt=8, s=512, b=2) -> 8192 blocks, 256 threads.
// Block handles 64 k values x all 12 heads; 4 threads per k (16 h each).
// rel tensors are read exactly once across the whole grid (HBM floor).
// ---------------------------------------------------------------------------
__global__ __launch_bounds__(256) void score_kernel(
    const float* __restrict__ qws, const float* __restrict__ kws,
    const float* __restrict__ rel1, const float* __restrict__ rel2, const float* __restrict__ rel3,
    const float* __restrict__ mask, float* __restrict__ scores)
{
    __shared__ float q_l[NH * HD];   // 3 KB

    const int kt  = blockIdx.x;
    const int s   = blockIdx.y;
    const int b   = blockIdx.z;
    const int tid = threadIdx.x;

    // Stage scaled q for all heads (threads 0..191).
    if (tid < 192) {
        const int n = tid >> 4, f = tid & 15;
        *(float4*)&q_l[n * 64 + f * 4] =
            *(const float4*)(qws + (((size_t)(b * NH + n) * S_) + s) * HD + f * 4);
    }
    __syncthreads();

    const int k  = kt * 64 + (tid >> 2);
    const int hq = (tid & 3) * 16;

    // Rsum = r1 + r2 + r3 for 16 h values.
    const size_t rbase = (((size_t)(b * S_ + s)) * S_ + k) * HD + hq;
    const float4* r1 = (const float4*)(rel1 + rbase);
    const float4* r2 = (const float4*)(rel2 + rbase);
    const float4* r3 = (const float4*)(rel3 + rbase);
    float4 rs[4];
    #pragma unroll
    for (int j = 0; j < 4; ++j) {
        float4 a = r1[j], bb = r2[j], c = r3[j];
        rs[j].x = a.x + bb.x + c.x;
        rs[j].y = a.y + bb.y + c.y;
        rs[j].z = a.z + bb.z + c.z;
        rs[j].w = a.w + bb.w + c.w;
    }
    const float msk = mask[b * S_ + k];

    #pragma unroll 3
    for (int n = 0; n < NH; ++n) {
        const float4* kp = (const float4*)(kws + (((size_t)(b * NH + n) * S_) + k) * HD + hq);
        const float4* qp = (const float4*)(&q_l[n * 64 + hq]);
        float p = 0.f;
        #pragma unroll
        for (int j = 0; j < 4; ++j) {
            float4 kv = kp[j];
            float4 qv = qp[j];
            p += qv.x * (kv.x + rs[j].x) + qv.y * (kv.y + rs[j].y)
               + qv.z * (kv.z + rs[j].z) + qv.w * (kv.w + rs[j].w);
        }
        p += __shfl_xor(p, 1);
        p += __shfl_xor(p, 2);
        if ((tid & 3) == 0)
            scores[(((size_t)(b * NH + n) * S_) + s) * S_ + k] = p + msk;
    }
}

// ---------------------------------------------------------------------------
// Kernel 3: fused softmax + PV. Grid (st=32, n=12, b=2) = 768 blocks.
// Block: 16 s-rows of one head. Wave w owns rows w*4..w*4+3 in both phases.
// ---------------------------------------------------------------------------
__global__ __launch_bounds__(256) void smpv_kernel(
    const float* __restrict__ scores, const float* __restrict__ vws,
    float* __restrict__ out)
{
    __shared__ float sc[16][512];    // 32 KB

    const int st  = blockIdx.x;
    const int n   = blockIdx.y;
    const int b   = blockIdx.z;
    const int s0  = st * 16;
    const int tid = threadIdx.x;

    const size_t base = (((size_t)(b * NH + n) * S_) + s0) * S_;

    // Stage 16 rows of scores (8192 floats) cooperatively.
    #pragma unroll
    for (int j = 0; j < 8; ++j) {
        const int fidx = j * 256 + tid;          // float4 index, 2048 total
        const int row  = fidx >> 7;
        const int c4   = fidx & 127;
        float4 v = *(const float4*)(scores + base + (size_t)row * S_ + c4 * 4);
        *(float4*)&sc[row][c4 * 4] = v;
    }
    __syncthreads();

    const int w = tid >> 6, lane = tid & 63;

    // Softmax on this wave's 4 rows (PB-Relax == plain softmax, shift-invariant).
    for (int r = 0; r < 4; ++r) {
        const int row = w * 4 + r;
        float vals[8];
        float m = -1e30f;
        #pragma unroll
        for (int i = 0; i < 8; ++i) { vals[i] = sc[row][lane + 64 * i]; m = fmaxf(m, vals[i]); }
        #pragma unroll
        for (int off = 32; off >= 1; off >>= 1) m = fmaxf(m, __shfl_xor(m, off));
        float sum = 0.f;
        #pragma unroll
        for (int i = 0; i < 8; ++i) { vals[i] = __expf(vals[i] - m); sum += vals[i]; }
        #pragma unroll
        for (int off = 32; off >= 1; off >>= 1) sum += __shfl_xor(sum, off);
        const float inv = 1.0f / sum;
        #pragma unroll
        for (int i = 0; i < 8; ++i) sc[row][lane + 64 * i] = vals[i] * inv;
    }
    __syncthreads();

    // PV: acc[r] = sum_k probs[row][k] * V[k][lane].
    float acc[4] = {0.f, 0.f, 0.f, 0.f};
    const float* vb = vws + (((size_t)(b * NH + n) * S_)) * HD + lane;
    for (int k = 0; k < S_; k += 4) {
        const float v0 = vb[(size_t)(k + 0) * HD];
        const float v1 = vb[(size_t)(k + 1) * HD];
        const float v2 = vb[(size_t)(k + 2) * HD];
        const float v3 = vb[(size_t)(k + 3) * HD];
        #pragma unroll
        for (int r = 0; r < 4; ++r) {
            float4 p = *(const float4*)&sc[w * 4 + r][k];
            acc[r] += p.x * v0 + p.y * v1 + p.z * v2 + p.w * v3;
        }
    }
    #pragma unroll
    for (int r = 0; r < 4; ++r)
        out[((size_t)(b * S_ + s0 + w * 4 + r)) * D_ + n * HD + lane] = acc[r];
}

extern "C" void kernel_launch(void* const* d_in, const int* in_sizes, int n_in,
                              void* d_out, int out_size, void* d_ws, size_t ws_size,
                              hipStream_t stream) {
    const float* hidden = (const float*)d_in[0];
    const float* mask   = (const float*)d_in[1];
    const float* rel1   = (const float*)d_in[2];
    const float* rel2   = (const float*)d_in[3];
    const float* rel3   = (const float*)d_in[4];
    const float* Wq     = (const float*)d_in[5];
    const float* bq     = (const float*)d_in[6];
    const float* Wk     = (const float*)d_in[7];
    const float* bk     = (const float*)d_in[8];
    const float* Wv     = (const float*)d_in[9];
    const float* bv     = (const float*)d_in[10];
    float* out = (float*)d_out;

    const size_t per = (size_t)B_ * NH * S_ * HD;   // 786432 floats
    float* qws    = (float*)d_ws;
    float* kws    = qws + per;
    float* vws    = kws + per;
    float* scores = vws + per;                       // 6291456 floats (25 MB)

    dim3 ggrid(B_ * S_ / 64, 36);
    qkv_gemm<<<ggrid, 256, 0, stream>>>(hidden, Wq, Wk, Wv, bq, bk, bv, qws, kws, vws);

    dim3 sgrid(S_ / 64, S_, B_);
    score_kernel<<<sgrid, 256, 0, stream>>>(qws, kws, rel1, rel2, rel3, mask, scores);

    dim3 pgrid(S_ / 16, NH, B_);
    smpv_kernel<<<pgrid, 256, 0, stream>>>(scores, vws, out);
}

// Round 3
// 164.431 us; speedup vs baseline: 3.0348x; 1.5962x over previous
//
#include <hip/hip_runtime.h>

typedef __attribute__((ext_vector_type(8))) short short8;
typedef __attribute__((ext_vector_type(4))) float f32x4;

#define B_ 2
#define S_ 512
#define D_ 768
#define NH 12
#define HD 64

__device__ inline short f2bf(float f) {
    union { float f; unsigned u; } v; v.f = f;
    unsigned r = v.u + 0x7fffu + ((v.u >> 16) & 1u);
    return (short)(r >> 16);
}

// ---------------------------------------------------------------------------
// Kernel 1: QKV projection, bf16 MFMA (16x16x32), fp32 accumulate.
// C[m][n] = hidden[m][:] . W[n][:] + bias. 64x64 tile, K=768 in 12 steps.
// q -> qbf (bf16, pre-scaled 1/8), k -> kbf (bf16), v -> vws (fp32),
// all in (B, NH, S, HD) layout.
// ---------------------------------------------------------------------------
__global__ __launch_bounds__(256) void qkv_gemm(
    const float* __restrict__ hidden,
    const float* __restrict__ Wq, const float* __restrict__ Wk, const float* __restrict__ Wv,
    const float* __restrict__ bq, const float* __restrict__ bk, const float* __restrict__ bv,
    short* __restrict__ qbf, short* __restrict__ kbf, float* __restrict__ vws)
{
    __shared__ short hs[64 * 72];
    __shared__ short wt[64 * 72];

    const int mt = blockIdx.x, nt = blockIdx.y, mat = blockIdx.z;
    const int m0 = mt * 64, n0 = nt * 64;
    const float* W    = (mat == 0) ? Wq : ((mat == 1) ? Wk : Wv);
    const float* bias = (mat == 0) ? bq : ((mat == 1) ? bk : bv);

    const int tid = threadIdx.x;
    const int w = tid >> 6, l = tid & 63;
    const int sr = tid >> 2, sc = (tid & 3) * 16;

    f32x4 acc[4];
    #pragma unroll
    for (int i = 0; i < 4; ++i) acc[i] = (f32x4){0.f, 0.f, 0.f, 0.f};

    const int arow = (w * 16 + (l & 15)) * 72 + (l >> 4) * 8;

    for (int kt = 0; kt < 12; ++kt) {
        const int d0 = kt * 64;
        if (kt) __syncthreads();
        {
            const float4* sa = (const float4*)(hidden + (size_t)(m0 + sr) * D_ + d0 + sc);
            float4 x0 = sa[0], x1 = sa[1], x2 = sa[2], x3 = sa[3];
            short8 p0 = {f2bf(x0.x), f2bf(x0.y), f2bf(x0.z), f2bf(x0.w),
                         f2bf(x1.x), f2bf(x1.y), f2bf(x1.z), f2bf(x1.w)};
            short8 p1 = {f2bf(x2.x), f2bf(x2.y), f2bf(x2.z), f2bf(x2.w),
                         f2bf(x3.x), f2bf(x3.y), f2bf(x3.z), f2bf(x3.w)};
            *(short8*)&hs[sr * 72 + sc]     = p0;
            *(short8*)&hs[sr * 72 + sc + 8] = p1;
            const float4* sb = (const float4*)(W + (size_t)(n0 + sr) * D_ + d0 + sc);
            float4 y0 = sb[0], y1 = sb[1], y2 = sb[2], y3 = sb[3];
            short8 q0 = {f2bf(y0.x), f2bf(y0.y), f2bf(y0.z), f2bf(y0.w),
                         f2bf(y1.x), f2bf(y1.y), f2bf(y1.z), f2bf(y1.w)};
            short8 q1 = {f2bf(y2.x), f2bf(y2.y), f2bf(y2.z), f2bf(y2.w),
                         f2bf(y3.x), f2bf(y3.y), f2bf(y3.z), f2bf(y3.w)};
            *(short8*)&wt[sr * 72 + sc]     = q0;
            *(short8*)&wt[sr * 72 + sc + 8] = q1;
        }
        __syncthreads();
        short8 a0 = *(const short8*)&hs[arow];
        short8 a1 = *(const short8*)&hs[arow + 32];
        #pragma unroll
        for (int ct = 0; ct < 4; ++ct) {
            const int brow = (ct * 16 + (l & 15)) * 72 + (l >> 4) * 8;
            short8 b0 = *(const short8*)&wt[brow];
            short8 b1 = *(const short8*)&wt[brow + 32];
            acc[ct] = __builtin_amdgcn_mfma_f32_16x16x32_bf16(a0, b0, acc[ct], 0, 0, 0);
            acc[ct] = __builtin_amdgcn_mfma_f32_16x16x32_bf16(a1, b1, acc[ct], 0, 0, 0);
        }
    }

    #pragma unroll
    for (int ct = 0; ct < 4; ++ct) {
        #pragma unroll
        for (int rr = 0; rr < 4; ++rr) {
            const int m_l = w * 16 + (l >> 4) * 4 + rr;
            const int n_l = ct * 16 + (l & 15);
            const int m = m0 + m_l;
            const int b = m >> 9, s = m & 511;
            float v = acc[ct][rr] + bias[n0 + n_l];
            const size_t dst = (((size_t)(b * NH + nt) * S_) + s) * HD + n_l;
            if (mat == 0)      qbf[dst] = f2bf(v * 0.125f);
            else if (mat == 1) kbf[dst] = f2bf(v);
            else               vws[dst] = v;
        }
    }
}

// ---------------------------------------------------------------------------
// Kernel 2: scores = qs . K^T + mask, batched over (b,n). 64x64 tile, K=64.
// ---------------------------------------------------------------------------
__global__ __launch_bounds__(256) void score_qk(
    const short* __restrict__ qbf, const short* __restrict__ kbf,
    const float* __restrict__ mask, float* __restrict__ scores)
{
    __shared__ short qa[64 * 72];
    __shared__ short kb[64 * 72];

    const int st = blockIdx.x, ktile = blockIdx.y, z = blockIdx.z;
    const int b = z / NH, n = z % NH;
    const int s0 = st * 64, k0 = ktile * 64;
    const int tid = threadIdx.x;
    const int w = tid >> 6, l = tid & 63;
    const int sr = tid >> 2, sc = (tid & 3) * 16;

    {
        const short8* sa = (const short8*)(qbf + (((size_t)(b * NH + n) * S_) + s0 + sr) * HD + sc);
        *(short8*)&qa[sr * 72 + sc]     = sa[0];
        *(short8*)&qa[sr * 72 + sc + 8] = sa[1];
        const short8* sb = (const short8*)(kbf + (((size_t)(b * NH + n) * S_) + k0 + sr) * HD + sc);
        *(short8*)&kb[sr * 72 + sc]     = sb[0];
        *(short8*)&kb[sr * 72 + sc + 8] = sb[1];
    }
    __syncthreads();

    f32x4 acc[4];
    #pragma unroll
    for (int i = 0; i < 4; ++i) acc[i] = (f32x4){0.f, 0.f, 0.f, 0.f};

    const int arow = (w * 16 + (l & 15)) * 72 + (l >> 4) * 8;
    short8 a0 = *(const short8*)&qa[arow];
    short8 a1 = *(const short8*)&qa[arow + 32];
    #pragma unroll
    for (int ct = 0; ct < 4; ++ct) {
        const int brow = (ct * 16 + (l & 15)) * 72 + (l >> 4) * 8;
        short8 b0 = *(const short8*)&kb[brow];
        short8 b1 = *(const short8*)&kb[brow + 32];
        acc[ct] = __builtin_amdgcn_mfma_f32_16x16x32_bf16(a0, b0, acc[ct], 0, 0, 0);
        acc[ct] = __builtin_amdgcn_mfma_f32_16x16x32_bf16(a1, b1, acc[ct], 0, 0, 0);
    }

    #pragma unroll
    for (int ct = 0; ct < 4; ++ct) {
        const float mv = mask[b * S_ + k0 + ct * 16 + (l & 15)];
        #pragma unroll
        for (int rr = 0; rr < 4; ++rr) {
            const int s_l = w * 16 + (l >> 4) * 4 + rr;
            scores[(((size_t)(b * NH + n) * S_) + s0 + s_l) * S_ + k0 + ct * 16 + (l & 15)]
                = acc[ct][rr] + mv;
        }
    }
}

// ---------------------------------------------------------------------------
// Kernel 3: rel contribution. Block per (b,s). Stream Rsum = r1+r2+r3 into
// bf16 LDS tiles (256 k x 64 h), MFMA against q A-fragment (loaded once),
// read-modify-write into scores.
// ---------------------------------------------------------------------------
__global__ __launch_bounds__(256) void score_rel(
    const short* __restrict__ qbf,
    const float* __restrict__ rel1, const float* __restrict__ rel2, const float* __restrict__ rel3,
    float* __restrict__ scores)
{
    __shared__ short ql[16 * 72];     // q rows 0..11 real, 12..15 zero
    __shared__ short rs[256 * 72];    // 36 KB

    const int s = blockIdx.x;
    const int b = blockIdx.y;
    const int tid = threadIdx.x;
    const int w = tid >> 6, l = tid & 63;

    if (tid < 128) {
        const int n = tid >> 3, seg = (tid & 7) * 8;
        short8 v = {0, 0, 0, 0, 0, 0, 0, 0};
        if (n < NH)
            v = *(const short8*)(qbf + (((size_t)(b * NH + n) * S_) + s) * HD + seg);
        *(short8*)&ql[n * 72 + seg] = v;
    }
    __syncthreads();

    const int arow = (l & 15) * 72 + (l >> 4) * 8;
    short8 a0 = *(const short8*)&ql[arow];
    short8 a1 = *(const short8*)&ql[arow + 32];

    const size_t rbase = ((size_t)(b * S_ + s)) * S_ * HD;

    for (int kt = 0; kt < 2; ++kt) {
        if (kt) __syncthreads();
        // Stage Rsum tile: 256 k x 64 h. Dense 1KB-per-inst global loads.
        #pragma unroll
        for (int p = 0; p < 4; ++p) {
            #pragma unroll
            for (int j = 0; j < 4; ++j) {
                const int f  = j * 256 + tid;          // 0..1023
                const int kl = p * 64 + (f >> 4);      // 0..255
                const int h4 = (f & 15) * 4;
                const size_t off = rbase + (size_t)(kt * 256 + kl) * HD + h4;
                float4 v1 = *(const float4*)(rel1 + off);
                float4 v2 = *(const float4*)(rel2 + off);
                float4 v3 = *(const float4*)(rel3 + off);
                const short s0b = f2bf(v1.x + v2.x + v3.x);
                const short s1b = f2bf(v1.y + v2.y + v3.y);
                const short s2b = f2bf(v1.z + v2.z + v3.z);
                const short s3b = f2bf(v1.w + v2.w + v3.w);
                unsigned lo = ((unsigned)(unsigned short)s0b) | (((unsigned)(unsigned short)s1b) << 16);
                unsigned hi = ((unsigned)(unsigned short)s2b) | (((unsigned)(unsigned short)s3b) << 16);
                uint2 pk; pk.x = lo; pk.y = hi;
                *(uint2*)&rs[kl * 72 + h4] = pk;
            }
        }
        __syncthreads();

        f32x4 acc[4];
        #pragma unroll
        for (int i = 0; i < 4; ++i) acc[i] = (f32x4){0.f, 0.f, 0.f, 0.f};
        #pragma unroll
        for (int i = 0; i < 4; ++i) {
            const int kc = w * 4 + i;
            const int brow = (kc * 16 + (l & 15)) * 72 + (l >> 4) * 8;
            short8 b0 = *(const short8*)&rs[brow];
            short8 b1 = *(const short8*)&rs[brow + 32];
            acc[i] = __builtin_amdgcn_mfma_f32_16x16x32_bf16(a0, b0, acc[i], 0, 0, 0);
            acc[i] = __builtin_amdgcn_mfma_f32_16x16x32_bf16(a1, b1, acc[i], 0, 0, 0);
        }

        #pragma unroll
        for (int i = 0; i < 4; ++i) {
            const int kg = kt * 256 + (w * 4 + i) * 16 + (l & 15);
            #pragma unroll
            for (int rr = 0; rr < 4; ++rr) {
                const int n = (l >> 4) * 4 + rr;
                if (n < NH) {
                    float* p = scores + (((size_t)(b * NH + n) * S_) + s) * S_ + kg;
                    *p += acc[i][rr];
                }
            }
        }
    }
}

// ---------------------------------------------------------------------------
// Kernel 4: fused softmax + PV (fp32). Grid (st=32, n=12, b=2).
// ---------------------------------------------------------------------------
__global__ __launch_bounds__(256) void smpv_kernel(
    const float* __restrict__ scores, const float* __restrict__ vws,
    float* __restrict__ out)
{
    __shared__ float sc[16][512];

    const int st  = blockIdx.x;
    const int n   = blockIdx.y;
    const int b   = blockIdx.z;
    const int s0  = st * 16;
    const int tid = threadIdx.x;

    const size_t base = (((size_t)(b * NH + n) * S_) + s0) * S_;

    #pragma unroll
    for (int j = 0; j < 8; ++j) {
        const int fidx = j * 256 + tid;
        const int row  = fidx >> 7;
        const int c4   = fidx & 127;
        float4 v = *(const float4*)(scores + base + (size_t)row * S_ + c4 * 4);
        *(float4*)&sc[row][c4 * 4] = v;
    }
    __syncthreads();

    const int w = tid >> 6, lane = tid & 63;

    for (int r = 0; r < 4; ++r) {
        const int row = w * 4 + r;
        float vals[8];
        float m = -1e30f;
        #pragma unroll
        for (int i = 0; i < 8; ++i) { vals[i] = sc[row][lane + 64 * i]; m = fmaxf(m, vals[i]); }
        #pragma unroll
        for (int off = 32; off >= 1; off >>= 1) m = fmaxf(m, __shfl_xor(m, off));
        float sum = 0.f;
        #pragma unroll
        for (int i = 0; i < 8; ++i) { vals[i] = __expf(vals[i] - m); sum += vals[i]; }
        #pragma unroll
        for (int off = 32; off >= 1; off >>= 1) sum += __shfl_xor(sum, off);
        const float inv = 1.0f / sum;
        #pragma unroll
        for (int i = 0; i < 8; ++i) sc[row][lane + 64 * i] = vals[i] * inv;
    }
    __syncthreads();

    float acc[4] = {0.f, 0.f, 0.f, 0.f};
    const float* vb = vws + (((size_t)(b * NH + n) * S_)) * HD + lane;
    for (int k = 0; k < S_; k += 4) {
        const float v0 = vb[(size_t)(k + 0) * HD];
        const float v1 = vb[(size_t)(k + 1) * HD];
        const float v2 = vb[(size_t)(k + 2) * HD];
        const float v3 = vb[(size_t)(k + 3) * HD];
        #pragma unroll
        for (int r = 0; r < 4; ++r) {
            float4 p = *(const float4*)&sc[w * 4 + r][k];
            acc[r] += p.x * v0 + p.y * v1 + p.z * v2 + p.w * v3;
        }
    }
    #pragma unroll
    for (int r = 0; r < 4; ++r)
        out[((size_t)(b * S_ + s0 + w * 4 + r)) * D_ + n * HD + lane] = acc[r];
}

extern "C" void kernel_launch(void* const* d_in, const int* in_sizes, int n_in,
                              void* d_out, int out_size, void* d_ws, size_t ws_size,
                              hipStream_t stream) {
    const float* hidden = (const float*)d_in[0];
    const float* mask   = (const float*)d_in[1];
    const float* rel1   = (const float*)d_in[2];
    const float* rel2   = (const float*)d_in[3];
    const float* rel3   = (const float*)d_in[4];
    const float* Wq     = (const float*)d_in[5];
    const float* bq     = (const float*)d_in[6];
    const float* Wk     = (const float*)d_in[7];
    const float* bk     = (const float*)d_in[8];
    const float* Wv     = (const float*)d_in[9];
    const float* bv     = (const float*)d_in[10];
    float* out = (float*)d_out;

    const size_t per = (size_t)B_ * NH * S_ * HD;   // 786432
    short* qbf    = (short*)d_ws;
    short* kbf    = qbf + per;
    float* vws    = (float*)(kbf + per);
    float* scores = vws + per;                       // 25 MB

    qkv_gemm<<<dim3(16, 12, 3), 256, 0, stream>>>(hidden, Wq, Wk, Wv, bq, bk, bv, qbf, kbf, vws);
    score_qk<<<dim3(8, 8, 24), 256, 0, stream>>>(qbf, kbf, mask, scores);
    score_rel<<<dim3(S_, B_), 256, 0, stream>>>(qbf, rel1, rel2, rel3, scores);
    smpv_kernel<<<dim3(S_ / 16, NH, B_), 256, 0, stream>>>(scores, vws, out);
}

// Round 4
// 162.053 us; speedup vs baseline: 3.0794x; 1.0147x over previous
//
#include <hip/hip_runtime.h>

typedef __attribute__((ext_vector_type(8))) short short8;
typedef __attribute__((ext_vector_type(4))) float f32x4;

#define B_ 2
#define S_ 512
#define D_ 768
#define NH 12
#define HD 64

__device__ inline short f2bf(float f) {
    union { float f; unsigned u; } v; v.f = f;
    unsigned r = v.u + 0x7fffu + ((v.u >> 16) & 1u);
    return (short)(r >> 16);
}

// ---------------------------------------------------------------------------
// Kernel 1: QKV projection, bf16 MFMA (16x16x32), fp32 accumulate.
// q -> qbf (bf16, pre-scaled 1/8), k -> kbf (bf16), v -> vws (fp32),
// all in (B, NH, S, HD) layout.
// ---------------------------------------------------------------------------
__global__ __launch_bounds__(256) void qkv_gemm(
    const float* __restrict__ hidden,
    const float* __restrict__ Wq, const float* __restrict__ Wk, const float* __restrict__ Wv,
    const float* __restrict__ bq, const float* __restrict__ bk, const float* __restrict__ bv,
    short* __restrict__ qbf, short* __restrict__ kbf, float* __restrict__ vws)
{
    __shared__ short hs[64 * 72];
    __shared__ short wt[64 * 72];

    const int mt = blockIdx.x, nt = blockIdx.y, mat = blockIdx.z;
    const int m0 = mt * 64, n0 = nt * 64;
    const float* W    = (mat == 0) ? Wq : ((mat == 1) ? Wk : Wv);
    const float* bias = (mat == 0) ? bq : ((mat == 1) ? bk : bv);

    const int tid = threadIdx.x;
    const int w = tid >> 6, l = tid & 63;
    const int sr = tid >> 2, sc = (tid & 3) * 16;

    f32x4 acc[4];
    #pragma unroll
    for (int i = 0; i < 4; ++i) acc[i] = (f32x4){0.f, 0.f, 0.f, 0.f};

    const int arow = (w * 16 + (l & 15)) * 72 + (l >> 4) * 8;

    for (int kt = 0; kt < 12; ++kt) {
        const int d0 = kt * 64;
        if (kt) __syncthreads();
        {
            const float4* sa = (const float4*)(hidden + (size_t)(m0 + sr) * D_ + d0 + sc);
            float4 x0 = sa[0], x1 = sa[1], x2 = sa[2], x3 = sa[3];
            short8 p0 = {f2bf(x0.x), f2bf(x0.y), f2bf(x0.z), f2bf(x0.w),
                         f2bf(x1.x), f2bf(x1.y), f2bf(x1.z), f2bf(x1.w)};
            short8 p1 = {f2bf(x2.x), f2bf(x2.y), f2bf(x2.z), f2bf(x2.w),
                         f2bf(x3.x), f2bf(x3.y), f2bf(x3.z), f2bf(x3.w)};
            *(short8*)&hs[sr * 72 + sc]     = p0;
            *(short8*)&hs[sr * 72 + sc + 8] = p1;
            const float4* sb = (const float4*)(W + (size_t)(n0 + sr) * D_ + d0 + sc);
            float4 y0 = sb[0], y1 = sb[1], y2 = sb[2], y3 = sb[3];
            short8 q0 = {f2bf(y0.x), f2bf(y0.y), f2bf(y0.z), f2bf(y0.w),
                         f2bf(y1.x), f2bf(y1.y), f2bf(y1.z), f2bf(y1.w)};
            short8 q1 = {f2bf(y2.x), f2bf(y2.y), f2bf(y2.z), f2bf(y2.w),
                         f2bf(y3.x), f2bf(y3.y), f2bf(y3.z), f2bf(y3.w)};
            *(short8*)&wt[sr * 72 + sc]     = q0;
            *(short8*)&wt[sr * 72 + sc + 8] = q1;
        }
        __syncthreads();
        short8 a0 = *(const short8*)&hs[arow];
        short8 a1 = *(const short8*)&hs[arow + 32];
        #pragma unroll
        for (int ct = 0; ct < 4; ++ct) {
            const int brow = (ct * 16 + (l & 15)) * 72 + (l >> 4) * 8;
            short8 b0 = *(const short8*)&wt[brow];
            short8 b1 = *(const short8*)&wt[brow + 32];
            acc[ct] = __builtin_amdgcn_mfma_f32_16x16x32_bf16(a0, b0, acc[ct], 0, 0, 0);
            acc[ct] = __builtin_amdgcn_mfma_f32_16x16x32_bf16(a1, b1, acc[ct], 0, 0, 0);
        }
    }

    #pragma unroll
    for (int ct = 0; ct < 4; ++ct) {
        #pragma unroll
        for (int rr = 0; rr < 4; ++rr) {
            const int m_l = w * 16 + (l >> 4) * 4 + rr;
            const int n_l = ct * 16 + (l & 15);
            const int m = m0 + m_l;
            const int b = m >> 9, s = m & 511;
            float v = acc[ct][rr] + bias[n0 + n_l];
            const size_t dst = (((size_t)(b * NH + nt) * S_) + s) * HD + n_l;
            if (mat == 0)      qbf[dst] = f2bf(v * 0.125f);
            else if (mat == 1) kbf[dst] = f2bf(v);
            else               vws[dst] = v;
        }
    }
}

// ---------------------------------------------------------------------------
// Kernel 2: scores = qs . K^T + mask, batched over (b,n). 64x64 tile.
// ---------------------------------------------------------------------------
__global__ __launch_bounds__(256) void score_qk(
    const short* __restrict__ qbf, const short* __restrict__ kbf,
    const float* __restrict__ mask, float* __restrict__ scores)
{
    __shared__ short qa[64 * 72];
    __shared__ short kb[64 * 72];

    const int st = blockIdx.x, ktile = blockIdx.y, z = blockIdx.z;
    const int b = z / NH, n = z % NH;
    const int s0 = st * 64, k0 = ktile * 64;
    const int tid = threadIdx.x;
    const int w = tid >> 6, l = tid & 63;
    const int sr = tid >> 2, sc = (tid & 3) * 16;

    {
        const short8* sa = (const short8*)(qbf + (((size_t)(b * NH + n) * S_) + s0 + sr) * HD + sc);
        *(short8*)&qa[sr * 72 + sc]     = sa[0];
        *(short8*)&qa[sr * 72 + sc + 8] = sa[1];
        const short8* sb = (const short8*)(kbf + (((size_t)(b * NH + n) * S_) + k0 + sr) * HD + sc);
        *(short8*)&kb[sr * 72 + sc]     = sb[0];
        *(short8*)&kb[sr * 72 + sc + 8] = sb[1];
    }
    __syncthreads();

    f32x4 acc[4];
    #pragma unroll
    for (int i = 0; i < 4; ++i) acc[i] = (f32x4){0.f, 0.f, 0.f, 0.f};

    const int arow = (w * 16 + (l & 15)) * 72 + (l >> 4) * 8;
    short8 a0 = *(const short8*)&qa[arow];
    short8 a1 = *(const short8*)&qa[arow + 32];
    #pragma unroll
    for (int ct = 0; ct < 4; ++ct) {
        const int brow = (ct * 16 + (l & 15)) * 72 + (l >> 4) * 8;
        short8 b0 = *(const short8*)&kb[brow];
        short8 b1 = *(const short8*)&kb[brow + 32];
        acc[ct] = __builtin_amdgcn_mfma_f32_16x16x32_bf16(a0, b0, acc[ct], 0, 0, 0);
        acc[ct] = __builtin_amdgcn_mfma_f32_16x16x32_bf16(a1, b1, acc[ct], 0, 0, 0);
    }

    #pragma unroll
    for (int ct = 0; ct < 4; ++ct) {
        const float mv = mask[b * S_ + k0 + ct * 16 + (l & 15)];
        #pragma unroll
        for (int rr = 0; rr < 4; ++rr) {
            const int s_l = w * 16 + (l >> 4) * 4 + rr;
            scores[(((size_t)(b * NH + n) * S_) + s0 + s_l) * S_ + k0 + ct * 16 + (l & 15)]
                = acc[ct][rr] + mv;
        }
    }
}

// ---------------------------------------------------------------------------
// Kernel 3: rel contribution, no LDS. Grid (kt=4, s=512, b=2) = 4096 blocks.
// Each wave handles 2 k-subtiles of 16. B-fragments (Rsum, bf16) are built
// directly in registers from per-lane global loads:
//   lane l reads rel*[k = kc*16 + (l&15)][h = (l>>4)*8 .. +8) and (+32).
// q A-fragment loaded once per lane straight from qbf. RMW into scores.
// ---------------------------------------------------------------------------
__global__ __launch_bounds__(256) void score_rel(
    const short* __restrict__ qbf,
    const float* __restrict__ rel1, const float* __restrict__ rel2, const float* __restrict__ rel3,
    float* __restrict__ scores)
{
    const int kt = blockIdx.x;
    const int s  = blockIdx.y;
    const int b  = blockIdx.z;
    const int tid = threadIdx.x;
    const int w = tid >> 6, l = tid & 63;

    const int rowsel = l & 15;       // A: n-row / B: k-row / C: k-col
    const int hc     = (l >> 4) * 8; // h-chunk base

    // q A-fragment (rows 12..15 zero).
    short8 a0 = {0, 0, 0, 0, 0, 0, 0, 0};
    short8 a1 = {0, 0, 0, 0, 0, 0, 0, 0};
    if (rowsel < NH) {
        const short* qp = qbf + (((size_t)(b * NH + rowsel) * S_) + s) * HD;
        a0 = *(const short8*)(qp + hc);
        a1 = *(const short8*)(qp + hc + 32);
    }

    const size_t rbase = ((size_t)(b * S_ + s)) * S_ * HD;

    #pragma unroll
    for (int t = 0; t < 2; ++t) {
        const int kc = kt * 8 + w * 2 + t;
        const size_t ro = rbase + (size_t)(kc * 16 + rowsel) * HD + hc;

        // 12 independent dwordx4 loads.
        float4 p0a = *(const float4*)(rel1 + ro);
        float4 p0b = *(const float4*)(rel1 + ro + 4);
        float4 p1a = *(const float4*)(rel2 + ro);
        float4 p1b = *(const float4*)(rel2 + ro + 4);
        float4 p2a = *(const float4*)(rel3 + ro);
        float4 p2b = *(const float4*)(rel3 + ro + 4);
        float4 q0a = *(const float4*)(rel1 + ro + 32);
        float4 q0b = *(const float4*)(rel1 + ro + 36);
        float4 q1a = *(const float4*)(rel2 + ro + 32);
        float4 q1b = *(const float4*)(rel2 + ro + 36);
        float4 q2a = *(const float4*)(rel3 + ro + 32);
        float4 q2b = *(const float4*)(rel3 + ro + 36);

        short8 b0 = {
            f2bf(p0a.x + p1a.x + p2a.x), f2bf(p0a.y + p1a.y + p2a.y),
            f2bf(p0a.z + p1a.z + p2a.z), f2bf(p0a.w + p1a.w + p2a.w),
            f2bf(p0b.x + p1b.x + p2b.x), f2bf(p0b.y + p1b.y + p2b.y),
            f2bf(p0b.z + p1b.z + p2b.z), f2bf(p0b.w + p1b.w + p2b.w)};
        short8 b1 = {
            f2bf(q0a.x + q1a.x + q2a.x), f2bf(q0a.y + q1a.y + q2a.y),
            f2bf(q0a.z + q1a.z + q2a.z), f2bf(q0a.w + q1a.w + q2a.w),
            f2bf(q0b.x + q1b.x + q2b.x), f2bf(q0b.y + q1b.y + q2b.y),
            f2bf(q0b.z + q1b.z + q2b.z), f2bf(q0b.w + q1b.w + q2b.w)};

        f32x4 acc = (f32x4){0.f, 0.f, 0.f, 0.f};
        acc = __builtin_amdgcn_mfma_f32_16x16x32_bf16(a0, b0, acc, 0, 0, 0);
        acc = __builtin_amdgcn_mfma_f32_16x16x32_bf16(a1, b1, acc, 0, 0, 0);

        const int kg = kc * 16 + rowsel;
        #pragma unroll
        for (int rr = 0; rr < 4; ++rr) {
            const int n = (l >> 4) * 4 + rr;
            if (n < NH) {
                float* p = scores + (((size_t)(b * NH + n) * S_) + s) * S_ + kg;
                *p += acc[rr];
            }
        }
    }
}

// ---------------------------------------------------------------------------
// Kernel 4: fused softmax + PV (fp32). Grid (st=32, n=12, b=2).
// ---------------------------------------------------------------------------
__global__ __launch_bounds__(256) void smpv_kernel(
    const float* __restrict__ scores, const float* __restrict__ vws,
    float* __restrict__ out)
{
    __shared__ float sc[16][512];

    const int st  = blockIdx.x;
    const int n   = blockIdx.y;
    const int b   = blockIdx.z;
    const int s0  = st * 16;
    const int tid = threadIdx.x;

    const size_t base = (((size_t)(b * NH + n) * S_) + s0) * S_;

    #pragma unroll
    for (int j = 0; j < 8; ++j) {
        const int fidx = j * 256 + tid;
        const int row  = fidx >> 7;
        const int c4   = fidx & 127;
        float4 v = *(const float4*)(scores + base + (size_t)row * S_ + c4 * 4);
        *(float4*)&sc[row][c4 * 4] = v;
    }
    __syncthreads();

    const int w = tid >> 6, lane = tid & 63;

    for (int r = 0; r < 4; ++r) {
        const int row = w * 4 + r;
        float vals[8];
        float m = -1e30f;
        #pragma unroll
        for (int i = 0; i < 8; ++i) { vals[i] = sc[row][lane + 64 * i]; m = fmaxf(m, vals[i]); }
        #pragma unroll
        for (int off = 32; off >= 1; off >>= 1) m = fmaxf(m, __shfl_xor(m, off));
        float sum = 0.f;
        #pragma unroll
        for (int i = 0; i < 8; ++i) { vals[i] = __expf(vals[i] - m); sum += vals[i]; }
        #pragma unroll
        for (int off = 32; off >= 1; off >>= 1) sum += __shfl_xor(sum, off);
        const float inv = 1.0f / sum;
        #pragma unroll
        for (int i = 0; i < 8; ++i) sc[row][lane + 64 * i] = vals[i] * inv;
    }
    __syncthreads();

    float acc[4] = {0.f, 0.f, 0.f, 0.f};
    const float* vb = vws + (((size_t)(b * NH + n) * S_)) * HD + lane;
    for (int k = 0; k < S_; k += 4) {
        const float v0 = vb[(size_t)(k + 0) * HD];
        const float v1 = vb[(size_t)(k + 1) * HD];
        const float v2 = vb[(size_t)(k + 2) * HD];
        const float v3 = vb[(size_t)(k + 3) * HD];
        #pragma unroll
        for (int r = 0; r < 4; ++r) {
            float4 p = *(const float4*)&sc[w * 4 + r][k];
            acc[r] += p.x * v0 + p.y * v1 + p.z * v2 + p.w * v3;
        }
    }
    #pragma unroll
    for (int r = 0; r < 4; ++r)
        out[((size_t)(b * S_ + s0 + w * 4 + r)) * D_ + n * HD + lane] = acc[r];
}

extern "C" void kernel_launch(void* const* d_in, const int* in_sizes, int n_in,
                              void* d_out, int out_size, void* d_ws, size_t ws_size,
                              hipStream_t stream) {
    const float* hidden = (const float*)d_in[0];
    const float* mask   = (const float*)d_in[1];
    const float* rel1   = (const float*)d_in[2];
    const float* rel2   = (const float*)d_in[3];
    const float* rel3   = (const float*)d_in[4];
    const float* Wq     = (const float*)d_in[5];
    const float* bq     = (const float*)d_in[6];
    const float* Wk     = (const float*)d_in[7];
    const float* bk     = (const float*)d_in[8];
    const float* Wv     = (const float*)d_in[9];
    const float* bv     = (const float*)d_in[10];
    float* out = (float*)d_out;

    const size_t per = (size_t)B_ * NH * S_ * HD;   // 786432
    short* qbf    = (short*)d_ws;
    short* kbf    = qbf + per;
    float* vws    = (float*)(kbf + per);
    float* scores = vws + per;                       // 25 MB

    qkv_gemm<<<dim3(16, 12, 3), 256, 0, stream>>>(hidden, Wq, Wk, Wv, bq, bk, bv, qbf, kbf, vws);
    score_qk<<<dim3(8, 8, 24), 256, 0, stream>>>(qbf, kbf, mask, scores);
    score_rel<<<dim3(4, S_, B_), 256, 0, stream>>>(qbf, rel1, rel2, rel3, scores);
    smpv_kernel<<<dim3(S_ / 16, NH, B_), 256, 0, stream>>>(scores, vws, out);
}

// Round 5
// 156.560 us; speedup vs baseline: 3.1874x; 1.0351x over previous
//
#include <hip/hip_runtime.h>

typedef __attribute__((ext_vector_type(8))) short short8;
typedef __attribute__((ext_vector_type(4))) float f32x4;

#define B_ 2
#define S_ 512
#define D_ 768
#define NH 12
#define HD 64

__device__ inline short f2bf(float f) {
    union { float f; unsigned u; } v; v.f = f;
    unsigned r = v.u + 0x7fffu + ((v.u >> 16) & 1u);
    return (short)(r >> 16);
}

// ---------------------------------------------------------------------------
// Kernel 1: QKV projection, bf16 MFMA (16x16x32), fp32 accumulate.
// q -> qbf (bf16, pre-scaled 1/8), k -> kbf (bf16), v -> vws (fp32),
// all in (B, NH, S, HD) layout.
// ---------------------------------------------------------------------------
__global__ __launch_bounds__(256) void qkv_gemm(
    const float* __restrict__ hidden,
    const float* __restrict__ Wq, const float* __restrict__ Wk, const float* __restrict__ Wv,
    const float* __restrict__ bq, const float* __restrict__ bk, const float* __restrict__ bv,
    short* __restrict__ qbf, short* __restrict__ kbf, float* __restrict__ vws)
{
    __shared__ short hs[64 * 72];
    __shared__ short wt[64 * 72];

    const int mt = blockIdx.x, nt = blockIdx.y, mat = blockIdx.z;
    const int m0 = mt * 64, n0 = nt * 64;
    const float* W    = (mat == 0) ? Wq : ((mat == 1) ? Wk : Wv);
    const float* bias = (mat == 0) ? bq : ((mat == 1) ? bk : bv);

    const int tid = threadIdx.x;
    const int w = tid >> 6, l = tid & 63;
    const int sr = tid >> 2, sc = (tid & 3) * 16;

    f32x4 acc[4];
    #pragma unroll
    for (int i = 0; i < 4; ++i) acc[i] = (f32x4){0.f, 0.f, 0.f, 0.f};

    const int arow = (w * 16 + (l & 15)) * 72 + (l >> 4) * 8;

    for (int kt = 0; kt < 12; ++kt) {
        const int d0 = kt * 64;
        if (kt) __syncthreads();
        {
            const float4* sa = (const float4*)(hidden + (size_t)(m0 + sr) * D_ + d0 + sc);
            float4 x0 = sa[0], x1 = sa[1], x2 = sa[2], x3 = sa[3];
            short8 p0 = {f2bf(x0.x), f2bf(x0.y), f2bf(x0.z), f2bf(x0.w),
                         f2bf(x1.x), f2bf(x1.y), f2bf(x1.z), f2bf(x1.w)};
            short8 p1 = {f2bf(x2.x), f2bf(x2.y), f2bf(x2.z), f2bf(x2.w),
                         f2bf(x3.x), f2bf(x3.y), f2bf(x3.z), f2bf(x3.w)};
            *(short8*)&hs[sr * 72 + sc]     = p0;
            *(short8*)&hs[sr * 72 + sc + 8] = p1;
            const float4* sb = (const float4*)(W + (size_t)(n0 + sr) * D_ + d0 + sc);
            float4 y0 = sb[0], y1 = sb[1], y2 = sb[2], y3 = sb[3];
            short8 q0 = {f2bf(y0.x), f2bf(y0.y), f2bf(y0.z), f2bf(y0.w),
                         f2bf(y1.x), f2bf(y1.y), f2bf(y1.z), f2bf(y1.w)};
            short8 q1 = {f2bf(y2.x), f2bf(y2.y), f2bf(y2.z), f2bf(y2.w),
                         f2bf(y3.x), f2bf(y3.y), f2bf(y3.z), f2bf(y3.w)};
            *(short8*)&wt[sr * 72 + sc]     = q0;
            *(short8*)&wt[sr * 72 + sc + 8] = q1;
        }
        __syncthreads();
        short8 a0 = *(const short8*)&hs[arow];
        short8 a1 = *(const short8*)&hs[arow + 32];
        #pragma unroll
        for (int ct = 0; ct < 4; ++ct) {
            const int brow = (ct * 16 + (l & 15)) * 72 + (l >> 4) * 8;
            short8 b0 = *(const short8*)&wt[brow];
            short8 b1 = *(const short8*)&wt[brow + 32];
            acc[ct] = __builtin_amdgcn_mfma_f32_16x16x32_bf16(a0, b0, acc[ct], 0, 0, 0);
            acc[ct] = __builtin_amdgcn_mfma_f32_16x16x32_bf16(a1, b1, acc[ct], 0, 0, 0);
        }
    }

    #pragma unroll
    for (int ct = 0; ct < 4; ++ct) {
        #pragma unroll
        for (int rr = 0; rr < 4; ++rr) {
            const int m_l = w * 16 + (l >> 4) * 4 + rr;
            const int n_l = ct * 16 + (l & 15);
            const int m = m0 + m_l;
            const int b = m >> 9, s = m & 511;
            float v = acc[ct][rr] + bias[n0 + n_l];
            const size_t dst = (((size_t)(b * NH + nt) * S_) + s) * HD + n_l;
            if (mat == 0)      qbf[dst] = f2bf(v * 0.125f);
            else if (mat == 1) kbf[dst] = f2bf(v);
            else               vws[dst] = v;
        }
    }
}

// ---------------------------------------------------------------------------
// Kernel 2: scores = qs . K^T + mask, batched over (b,n). 64x64 tile.
// ---------------------------------------------------------------------------
__global__ __launch_bounds__(256) void score_qk(
    const short* __restrict__ qbf, const short* __restrict__ kbf,
    const float* __restrict__ mask, float* __restrict__ scores)
{
    __shared__ short qa[64 * 72];
    __shared__ short kb[64 * 72];

    const int st = blockIdx.x, ktile = blockIdx.y, z = blockIdx.z;
    const int b = z / NH, n = z % NH;
    const int s0 = st * 64, k0 = ktile * 64;
    const int tid = threadIdx.x;
    const int w = tid >> 6, l = tid & 63;
    const int sr = tid >> 2, sc = (tid & 3) * 16;

    {
        const short8* sa = (const short8*)(qbf + (((size_t)(b * NH + n) * S_) + s0 + sr) * HD + sc);
        *(short8*)&qa[sr * 72 + sc]     = sa[0];
        *(short8*)&qa[sr * 72 + sc + 8] = sa[1];
        const short8* sb = (const short8*)(kbf + (((size_t)(b * NH + n) * S_) + k0 + sr) * HD + sc);
        *(short8*)&kb[sr * 72 + sc]     = sb[0];
        *(short8*)&kb[sr * 72 + sc + 8] = sb[1];
    }
    __syncthreads();

    f32x4 acc[4];
    #pragma unroll
    for (int i = 0; i < 4; ++i) acc[i] = (f32x4){0.f, 0.f, 0.f, 0.f};

    const int arow = (w * 16 + (l & 15)) * 72 + (l >> 4) * 8;
    short8 a0 = *(const short8*)&qa[arow];
    short8 a1 = *(const short8*)&qa[arow + 32];
    #pragma unroll
    for (int ct = 0; ct < 4; ++ct) {
        const int brow = (ct * 16 + (l & 15)) * 72 + (l >> 4) * 8;
        short8 b0 = *(const short8*)&kb[brow];
        short8 b1 = *(const short8*)&kb[brow + 32];
        acc[ct] = __builtin_amdgcn_mfma_f32_16x16x32_bf16(a0, b0, acc[ct], 0, 0, 0);
        acc[ct] = __builtin_amdgcn_mfma_f32_16x16x32_bf16(a1, b1, acc[ct], 0, 0, 0);
    }

    #pragma unroll
    for (int ct = 0; ct < 4; ++ct) {
        const float mv = mask[b * S_ + k0 + ct * 16 + (l & 15)];
        #pragma unroll
        for (int rr = 0; rr < 4; ++rr) {
            const int s_l = w * 16 + (l >> 4) * 4 + rr;
            scores[(((size_t)(b * NH + n) * S_) + s0 + s_l) * S_ + k0 + ct * 16 + (l & 15)]
                = acc[ct][rr] + mv;
        }
    }
}

// ---------------------------------------------------------------------------
// Kernel 3: rel contribution, no LDS. Grid (kt=8, s=512, b=2) = 8192 blocks.
// One 16-k subtile per wave; all 12 dwordx4 loads issued before first use
// (launch_bounds(256,4) -> 128 VGPR budget so nothing serializes).
// B-fragments (Rsum, bf16) built in registers; q A-fragment from qbf; RMW
// into scores.
// ---------------------------------------------------------------------------
__global__ __launch_bounds__(256, 4) void score_rel(
    const short* __restrict__ qbf,
    const float* __restrict__ rel1, const float* __restrict__ rel2, const float* __restrict__ rel3,
    float* __restrict__ scores)
{
    const int kt = blockIdx.x;       // 0..7
    const int s  = blockIdx.y;
    const int b  = blockIdx.z;
    const int tid = threadIdx.x;
    const int w = tid >> 6, l = tid & 63;

    const int rowsel = l & 15;       // A: n-row / B: k-row / C: k-col
    const int hc     = (l >> 4) * 8; // h-chunk base

    const int kc = kt * 4 + w;       // k-subtile 0..31
    const size_t rbase = ((size_t)(b * S_ + s)) * S_ * HD;
    const size_t ro = rbase + (size_t)(kc * 16 + rowsel) * HD + hc;

    // 12 independent dwordx4 loads — issue all before any use.
    float4 p0a = *(const float4*)(rel1 + ro);
    float4 p0b = *(const float4*)(rel1 + ro + 4);
    float4 q0a = *(const float4*)(rel1 + ro + 32);
    float4 q0b = *(const float4*)(rel1 + ro + 36);
    float4 p1a = *(const float4*)(rel2 + ro);
    float4 p1b = *(const float4*)(rel2 + ro + 4);
    float4 q1a = *(const float4*)(rel2 + ro + 32);
    float4 q1b = *(const float4*)(rel2 + ro + 36);
    float4 p2a = *(const float4*)(rel3 + ro);
    float4 p2b = *(const float4*)(rel3 + ro + 4);
    float4 q2a = *(const float4*)(rel3 + ro + 32);
    float4 q2b = *(const float4*)(rel3 + ro + 36);

    // q A-fragment (rows 12..15 zero).
    short8 a0 = {0, 0, 0, 0, 0, 0, 0, 0};
    short8 a1 = {0, 0, 0, 0, 0, 0, 0, 0};
    if (rowsel < NH) {
        const short* qp = qbf + (((size_t)(b * NH + rowsel) * S_) + s) * HD;
        a0 = *(const short8*)(qp + hc);
        a1 = *(const short8*)(qp + hc + 32);
    }

    short8 b0 = {
        f2bf(p0a.x + p1a.x + p2a.x), f2bf(p0a.y + p1a.y + p2a.y),
        f2bf(p0a.z + p1a.z + p2a.z), f2bf(p0a.w + p1a.w + p2a.w),
        f2bf(p0b.x + p1b.x + p2b.x), f2bf(p0b.y + p1b.y + p2b.y),
        f2bf(p0b.z + p1b.z + p2b.z), f2bf(p0b.w + p1b.w + p2b.w)};
    short8 b1 = {
        f2bf(q0a.x + q1a.x + q2a.x), f2bf(q0a.y + q1a.y + q2a.y),
        f2bf(q0a.z + q1a.z + q2a.z), f2bf(q0a.w + q1a.w + q2a.w),
        f2bf(q0b.x + q1b.x + q2b.x), f2bf(q0b.y + q1b.y + q2b.y),
        f2bf(q0b.z + q1b.z + q2b.z), f2bf(q0b.w + q1b.w + q2b.w)};

    f32x4 acc = (f32x4){0.f, 0.f, 0.f, 0.f};
    acc = __builtin_amdgcn_mfma_f32_16x16x32_bf16(a0, b0, acc, 0, 0, 0);
    acc = __builtin_amdgcn_mfma_f32_16x16x32_bf16(a1, b1, acc, 0, 0, 0);

    const int kg = kc * 16 + rowsel;
    #pragma unroll
    for (int rr = 0; rr < 4; ++rr) {
        const int n = (l >> 4) * 4 + rr;
        if (n < NH) {
            float* p = scores + (((size_t)(b * NH + n) * S_) + s) * S_ + kg;
            *p += acc[rr];
        }
    }
}

// ---------------------------------------------------------------------------
// Kernel 4: fused softmax + PV (fp32). Grid (st=32, n=12, b=2).
// ---------------------------------------------------------------------------
__global__ __launch_bounds__(256) void smpv_kernel(
    const float* __restrict__ scores, const float* __restrict__ vws,
    float* __restrict__ out)
{
    __shared__ float sc[16][512];

    const int st  = blockIdx.x;
    const int n   = blockIdx.y;
    const int b   = blockIdx.z;
    const int s0  = st * 16;
    const int tid = threadIdx.x;

    const size_t base = (((size_t)(b * NH + n) * S_) + s0) * S_;

    #pragma unroll
    for (int j = 0; j < 8; ++j) {
        const int fidx = j * 256 + tid;
        const int row  = fidx >> 7;
        const int c4   = fidx & 127;
        float4 v = *(const float4*)(scores + base + (size_t)row * S_ + c4 * 4);
        *(float4*)&sc[row][c4 * 4] = v;
    }
    __syncthreads();

    const int w = tid >> 6, lane = tid & 63;

    for (int r = 0; r < 4; ++r) {
        const int row = w * 4 + r;
        float vals[8];
        float m = -1e30f;
        #pragma unroll
        for (int i = 0; i < 8; ++i) { vals[i] = sc[row][lane + 64 * i]; m = fmaxf(m, vals[i]); }
        #pragma unroll
        for (int off = 32; off >= 1; off >>= 1) m = fmaxf(m, __shfl_xor(m, off));
        float sum = 0.f;
        #pragma unroll
        for (int i = 0; i < 8; ++i) { vals[i] = __expf(vals[i] - m); sum += vals[i]; }
        #pragma unroll
        for (int off = 32; off >= 1; off >>= 1) sum += __shfl_xor(sum, off);
        const float inv = 1.0f / sum;
        #pragma unroll
        for (int i = 0; i < 8; ++i) sc[row][lane + 64 * i] = vals[i] * inv;
    }
    __syncthreads();

    float acc[4] = {0.f, 0.f, 0.f, 0.f};
    const float* vb = vws + (((size_t)(b * NH + n) * S_)) * HD + lane;
    for (int k = 0; k < S_; k += 4) {
        const float v0 = vb[(size_t)(k + 0) * HD];
        const float v1 = vb[(size_t)(k + 1) * HD];
        const float v2 = vb[(size_t)(k + 2) * HD];
        const float v3 = vb[(size_t)(k + 3) * HD];
        #pragma unroll
        for (int r = 0; r < 4; ++r) {
            float4 p = *(const float4*)&sc[w * 4 + r][k];
            acc[r] += p.x * v0 + p.y * v1 + p.z * v2 + p.w * v3;
        }
    }
    #pragma unroll
    for (int r = 0; r < 4; ++r)
        out[((size_t)(b * S_ + s0 + w * 4 + r)) * D_ + n * HD + lane] = acc[r];
}

extern "C" void kernel_launch(void* const* d_in, const int* in_sizes, int n_in,
                              void* d_out, int out_size, void* d_ws, size_t ws_size,
                              hipStream_t stream) {
    const float* hidden = (const float*)d_in[0];
    const float* mask   = (const float*)d_in[1];
    const float* rel1   = (const float*)d_in[2];
    const float* rel2   = (const float*)d_in[3];
    const float* rel3   = (const float*)d_in[4];
    const float* Wq     = (const float*)d_in[5];
    const float* bq     = (const float*)d_in[6];
    const float* Wk     = (const float*)d_in[7];
    const float* bk     = (const float*)d_in[8];
    const float* Wv     = (const float*)d_in[9];
    const float* bv     = (const float*)d_in[10];
    float* out = (float*)d_out;

    const size_t per = (size_t)B_ * NH * S_ * HD;   // 786432
    short* qbf    = (short*)d_ws;
    short* kbf    = qbf + per;
    float* vws    = (float*)(kbf + per);
    float* scores = vws + per;                       // 25 MB

    qkv_gemm<<<dim3(16, 12, 3), 256, 0, stream>>>(hidden, Wq, Wk, Wv, bq, bk, bv, qbf, kbf, vws);
    score_qk<<<dim3(8, 8, 24), 256, 0, stream>>>(qbf, kbf, mask, scores);
    score_rel<<<dim3(8, S_, B_), 256, 0, stream>>>(qbf, rel1, rel2, rel3, scores);
    smpv_kernel<<<dim3(S_ / 16, NH, B_), 256, 0, stream>>>(scores, vws, out);
}